// Round 19
// baseline (2351.795 us; speedup 1.0000x reference)
//
#include <hip/hip_runtime.h>

typedef _Float16 half8 __attribute__((ext_vector_type(8)));
typedef float floatx4 __attribute__((ext_vector_type(4)));
typedef unsigned int uintx4 __attribute__((ext_vector_type(4)));
typedef unsigned long long u64t;

#define B_ 64
#define S_ 512
#define H_ 1024

// Launch epoch base in .bss (zero at load). Block 0 tid 0 bumps it by 1024
// (> S_+1) at kernel END -- provably after every block's start-read (block0
// finishes only after consuming all blocks' tagged data, which is published
// only after those blocks read tagctr). Tags never repeat across launches;
// ws poison 0xAAAAAAAA never matches a live tag.  [r9/r12-proven]
__device__ unsigned tagctr;

__device__ __forceinline__ float sigmoidf_(float x) { return 1.0f / (1.0f + __expf(-x)); }
__device__ __forceinline__ float tanhf_(float x) {
    return 1.0f - 2.0f / (__expf(2.0f * x) + 1.0f);   // saturates correctly via __expf
}

// 256 blocks x 256 threads. Block (cb=bid&63, mb=bid>>6) owns the 16x16
// tile: batches [16mb,16mb+16) x cols [16cb,16cb+16), full K=1024; wave =
// K-quarter; K-reduce in double-buffered LDS -- ONE __syncthreads per step.
//
// r19 = r18 with the s_sleep literal-operand fix (r18 never ran).
// Protocol: r12's tagged-payload dataflow + r17's contention lesson.
// Publication unit = 8 B agent-relaxed word {tag32 | 2x f16 xi}. Publish is
// fire-and-forget (no drain, no barrier, no slots -- the 2 coherence legs
// r17 still paid). Consumer polls its 32 words with 16 forced
// global_load_dwordx4 sc1 (single pipelined burst = 1 LLC round-trip),
// checks the 32 inline tags; first retry is eager (s_sleep 1), later
// retries back off (s_sleep 8, ~0.2us) -- r12's continuous re-burst
// hammered the payload lines; r17 proved that contention costs ~1us/step.
//
// WAR safety of the 2-deep buffer (r12-proven): block X publishes step t+1
// only after its reduce-__syncthreads joined all 4 waves' step-t tag-polls;
// the 4 waves' source sets union to ALL 64 group publishers; each publisher
// raised tag t only after ITS reduce-sync, i.e. after its whole block
// finished reading buffer[(t-1)&1]. Per-word tags hide partial tiles.
__global__ void __launch_bounds__(256, 1)
lstm_scan(const float* __restrict__ emb, const float* __restrict__ W, const float* __restrict__ bW,
          const float* __restrict__ U, const float* __restrict__ bU,
          const float* __restrict__ V, const float* __restrict__ bV,
          float* __restrict__ out, unsigned char* __restrict__ ws)
{
    const int bid  = blockIdx.x;
    const int cb   = bid & 63;    // column group (16 H-cols)
    const int mb   = bid >> 6;    // batch group (16 batches)
    const int tid  = threadIdx.x;
    const int w    = tid >> 6;    // wave id = K-quarter
    const int lane = tid & 63;
    const int fr   = lane & 15;   // A-frag row index
    const int kg   = lane >> 4;   // A-frag k-block

    u64t* pub = (u64t*)ws;        // [2][64 rows][512 pairs] u64 = 512 KB

    __shared__ __align__(16) float part[2][4 * 3 * 64 * 4];   // 2 x 12 KB

    const unsigned e0 = __hip_atomic_load(&tagctr, __ATOMIC_RELAXED,
                                          __HIP_MEMORY_SCOPE_AGENT);

    // ---- persistent weight fragments (f16, registers): 3 gates x 8 ksteps ----
    // B-frag of mfma_f32_16x16x32_f16: lane l holds B[k=(l>>4)*8+e][n=l&15],
    // B[k][n] = Wgate[16*cb + n][k].  (Layout proven rounds 1/4-17.)
    half8 Bf[3][8];
    {
        const int jrow = cb * 16 + fr;
        const int kb   = w * 256 + kg * 8;
        const float* p0 = W + jrow * H_ + kb;
        const float* p1 = U + jrow * H_ + kb;
        const float* p2 = V + jrow * H_ + kb;
        #pragma unroll
        for (int ks = 0; ks < 8; ++ks) {
            half8 h0, h1, h2;
            #pragma unroll
            for (int e = 0; e < 8; ++e) {
                h0[e] = (_Float16)p0[ks * 32 + e];
                h1[e] = (_Float16)p1[ks * 32 + e];
                h2[e] = (_Float16)p2[ks * 32 + e];
            }
            Bf[0][ks] = h0; Bf[1][ks] = h1; Bf[2][ks] = h2;
        }
    }

    // ---- elementwise ownership: thread -> ONE cell (b, j) ----
    const int rt = tid >> 4;
    const int ct = tid & 15;
    const int b  = mb * 16 + rt;
    const int j  = cb * 16 + ct;
    const float bw = bW[j], bu = bU[j], bv = bV[j];
    const int rl = (rt >> 2) * 16 + ct;   // C/D source lane (proven)
    const int rr = rt & 3;                // C/D source reg
    const bool evenct = (ct & 1) == 0;
    const unsigned widx = (unsigned)(b * 512 + cb * 8 + (ct >> 1));  // pair slot

    // publish own xi (paired with ct^1 neighbor): one tagged 8B word,
    // fire-and-forget -- no drain, no barrier, no slot store.
    auto publish = [&](int buf, unsigned tag, float xin) {
        union { _Float16 h; unsigned short u; } cvp; cvp.h = (_Float16)xin;
        unsigned mine  = cvp.u;
        unsigned other = (unsigned)__shfl_xor((int)mine, 1);
        if (evenct)
            __hip_atomic_store(&pub[(unsigned)buf * (64 * 512) + widx],
                               ((u64t)tag << 32) | (u64t)(mine | (other << 16)),
                               __ATOMIC_RELAXED, __HIP_MEMORY_SCOPE_AGENT);
    };

    float p1s = 0.0f;
    float xio = emb[(b * S_ + 0) * H_ + j];    // p2 init = 0
    publish(0, e0 + 1u, xio);
    float embn = emb[(b * S_ + 1) * H_ + j];   // prefetch t=1

    for (int t = 0; t < S_; ++t) {
        const unsigned tag = e0 + (unsigned)t + 1u;
        // lane's 32 words: (mb*16+fr)*512 + w*128 + ks*16 + kg*4 + {0..3}
        const u64t* lanebase = pub + (unsigned)((t & 1) * (64 * 512)
                              + (mb * 16 + fr) * 512 + w * 128 + kg * 4);

        // ---- batch poll: 16 forced dwordx4 sc1 loads = 1 round-trip ----
        uintx4 l0, l1, l2, l3, l4, l5, l6, l7, l8, l9, lA, lB, lC, lD, lE, lF;
        bool first = true;
        for (;;) {
            asm volatile("global_load_dwordx4 %0, %1, off sc1"            : "=v"(l0) : "v"(lanebase));
            asm volatile("global_load_dwordx4 %0, %1, off offset:16 sc1"  : "=v"(l1) : "v"(lanebase));
            asm volatile("global_load_dwordx4 %0, %1, off offset:128 sc1" : "=v"(l2) : "v"(lanebase));
            asm volatile("global_load_dwordx4 %0, %1, off offset:144 sc1" : "=v"(l3) : "v"(lanebase));
            asm volatile("global_load_dwordx4 %0, %1, off offset:256 sc1" : "=v"(l4) : "v"(lanebase));
            asm volatile("global_load_dwordx4 %0, %1, off offset:272 sc1" : "=v"(l5) : "v"(lanebase));
            asm volatile("global_load_dwordx4 %0, %1, off offset:384 sc1" : "=v"(l6) : "v"(lanebase));
            asm volatile("global_load_dwordx4 %0, %1, off offset:400 sc1" : "=v"(l7) : "v"(lanebase));
            asm volatile("global_load_dwordx4 %0, %1, off offset:512 sc1" : "=v"(l8) : "v"(lanebase));
            asm volatile("global_load_dwordx4 %0, %1, off offset:528 sc1" : "=v"(l9) : "v"(lanebase));
            asm volatile("global_load_dwordx4 %0, %1, off offset:640 sc1" : "=v"(lA) : "v"(lanebase));
            asm volatile("global_load_dwordx4 %0, %1, off offset:656 sc1" : "=v"(lB) : "v"(lanebase));
            asm volatile("global_load_dwordx4 %0, %1, off offset:768 sc1" : "=v"(lC) : "v"(lanebase));
            asm volatile("global_load_dwordx4 %0, %1, off offset:784 sc1" : "=v"(lD) : "v"(lanebase));
            asm volatile("global_load_dwordx4 %0, %1, off offset:896 sc1" : "=v"(lE) : "v"(lanebase));
            asm volatile("global_load_dwordx4 %0, %1, off offset:912 sc1" : "=v"(lF) : "v"(lanebase));
            asm volatile("s_waitcnt vmcnt(0)" ::: "memory");
            __builtin_amdgcn_sched_barrier(0);       // rule #18
            // dwordx4 = [data_p0, tag_p0, data_p1, tag_p1]
            bool ok = (l0[1] == tag) & (l0[3] == tag) & (l1[1] == tag) & (l1[3] == tag)
                    & (l2[1] == tag) & (l2[3] == tag) & (l3[1] == tag) & (l3[3] == tag)
                    & (l4[1] == tag) & (l4[3] == tag) & (l5[1] == tag) & (l5[3] == tag)
                    & (l6[1] == tag) & (l6[3] == tag) & (l7[1] == tag) & (l7[3] == tag)
                    & (l8[1] == tag) & (l8[3] == tag) & (l9[1] == tag) & (l9[3] == tag)
                    & (lA[1] == tag) & (lA[3] == tag) & (lB[1] == tag) & (lB[3] == tag)
                    & (lC[1] == tag) & (lC[3] == tag) & (lD[1] == tag) & (lD[3] == tag)
                    & (lE[1] == tag) & (lE[3] == tag) & (lF[1] == tag) & (lF[3] == tag);
            if (__all(ok)) break;
            // backoff: eager first retry, then ~0.2us sleeps (s_sleep needs
            // a literal operand -> two constant calls behind a branch).
            if (first) { __builtin_amdgcn_s_sleep(1); first = false; }
            else       { __builtin_amdgcn_s_sleep(8); }
        }

        // ---- MFMA from captured registers ----
        floatx4 a0 = {0.f, 0.f, 0.f, 0.f};
        floatx4 a1 = {0.f, 0.f, 0.f, 0.f};
        floatx4 a2 = {0.f, 0.f, 0.f, 0.f};
        union { unsigned u[4]; half8 h; } cv;
        #define DO_KS(ks, A, Bv)                                               \
        {                                                                      \
            cv.u[0] = A[0]; cv.u[1] = A[2]; cv.u[2] = Bv[0]; cv.u[3] = Bv[2];  \
            a0 = __builtin_amdgcn_mfma_f32_16x16x32_f16(cv.h, Bf[0][ks], a0, 0, 0, 0); \
            a1 = __builtin_amdgcn_mfma_f32_16x16x32_f16(cv.h, Bf[1][ks], a1, 0, 0, 0); \
            a2 = __builtin_amdgcn_mfma_f32_16x16x32_f16(cv.h, Bf[2][ks], a2, 0, 0, 0); \
        }
        DO_KS(0, l0, l1) DO_KS(1, l2, l3) DO_KS(2, l4, l5) DO_KS(3, l6, l7)
        DO_KS(4, l8, l9) DO_KS(5, lA, lB) DO_KS(6, lC, lD) DO_KS(7, lE, lF)
        #undef DO_KS

        // ---- K-reduction in LDS (double-buffered -> one sync per step) ----
        float* pp = part[t & 1];
        *(floatx4*)&pp[((w * 3 + 0) * 64 + lane) * 4] = a0;
        *(floatx4*)&pp[((w * 3 + 1) * 64 + lane) * 4] = a1;
        *(floatx4*)&pp[((w * 3 + 2) * 64 + lane) * 4] = a2;
        __syncthreads();

        float pf = bw, pu = bu, pv = bv;
        #pragma unroll
        for (int wv = 0; wv < 4; ++wv) {
            pf += pp[((wv * 3 + 0) * 64 + rl) * 4 + rr];
            pu += pp[((wv * 3 + 1) * 64 + rl) * 4 + rr];
            pv += pp[((wv * 3 + 2) * 64 + rl) * 4 + rr];
        }

        // ---- gates + state update ----
        float fg = sigmoidf_(pf);
        float ig = sigmoidf_(pu);
        float gg = tanhf_(pv);
        p1s = fg * p1s + ig * gg;
        float p2 = sigmoidf_(xio) * tanhf_(p1s);

        if (t < S_ - 1) {
            float xin = embn + p2;
            xio = xin;
            publish((t + 1) & 1, e0 + (unsigned)t + 2u, xin);   // fire & forget
            __builtin_nontemporal_store(p2, &out[(b * S_ + t) * H_ + j]);
            if (t + 2 < S_) embn = emb[(b * S_ + t + 2) * H_ + j];
        } else {
            __builtin_nontemporal_store(p2, &out[(b * S_ + t) * H_ + j]);
        }
    }

    // bump epoch base for the next launch (after all communication done)
    if (bid == 0 && tid == 0)
        __hip_atomic_store(&tagctr, e0 + 1024u, __ATOMIC_RELAXED,
                           __HIP_MEMORY_SCOPE_AGENT);
}

extern "C" void kernel_launch(void* const* d_in, const int* in_sizes, int n_in,
                              void* d_out, int out_size, void* d_ws, size_t ws_size,
                              hipStream_t stream)
{
    const float* emb = (const float*)d_in[0];
    const float* W   = (const float*)d_in[1];
    const float* bWv = (const float*)d_in[2];
    const float* U   = (const float*)d_in[3];
    const float* bUv = (const float*)d_in[4];
    const float* V   = (const float*)d_in[5];
    const float* bVv = (const float*)d_in[6];
    float* outp = (float*)d_out;
    unsigned char* ws = (unsigned char*)d_ws;
    (void)in_sizes; (void)n_in; (void)out_size; (void)ws_size;

    void* args[] = {(void*)&emb, (void*)&W, (void*)&bWv, (void*)&U, (void*)&bUv,
                    (void*)&V, (void*)&bVv, (void*)&outp, (void*)&ws};
    hipError_t err = hipLaunchCooperativeKernel((const void*)lstm_scan,
                                                dim3(256), dim3(256), args, 0, stream);
    if (err != hipSuccess) {
        lstm_scan<<<dim3(256), dim3(256), 0, stream>>>(emb, W, bWv, U, bUv, V, bVv, outp, ws);
    }
}

// Round 21
// 1554.816 us; speedup vs baseline: 1.5126x; 1.5126x over previous
//
#include <hip/hip_runtime.h>

typedef _Float16 half8 __attribute__((ext_vector_type(8)));
typedef float floatx4 __attribute__((ext_vector_type(4)));
typedef unsigned int uintx4 __attribute__((ext_vector_type(4)));
typedef unsigned long long u64t;

#define B_ 64
#define S_ 512
#define H_ 1024

// Arrival slots, padded to one 64B line each (r17-proven: kills poll-line
// contention). .bss: zero at load, untouched by ws poison. Monotonic: each
// block's slot advances by exactly S_ per launch. Per-launch base e0 = own
// slot value read before any arrival.
__device__ unsigned slotP[4][64][16];

__device__ __forceinline__ float sigmoidf_(float x) { return 1.0f / (1.0f + __expf(-x)); }
__device__ __forceinline__ float tanhf_(float x) {
    return 1.0f - 2.0f / (__expf(2.0f * x) + 1.0f);   // saturates correctly via __expf
}

// 256 blocks x 256 threads -- r17 VERBATIM (best measured: 1.56 ms) except:
//  1. per-wave quarter poll: wave w polls only its 16 source blocks
//     (lanes<16; __all is a wave-wide vote so the wave exits together).
//     Each wave bursts as soon as ITS sources are ready (straggler overlap)
//     and r17's post-wait release __syncthreads disappears. Total poll
//     traffic unchanged (64 loads/block/retry).
//  2. backoff s_sleep(4) (~0.1us quantum, was 8).
// r20's asm-housekeeping is REVERTED (rule-18 hazard: asm load results
// consumed across compiler-invisible waits corrupted xi -- absmax 1.75).
// All housekeeping is plain C++ (compiler inserts the waits at first use).
//
// Geometry: block (cb=bid&63, mb=bid>>6) owns the 16x16 tile: batches
// [16mb,16mb+16) x cols [16cb,16cb+16), full K=1024; wave = K-quarter;
// K-reduce in double-buffered LDS (one reduce-__syncthreads per step);
// publish = packed 8B sc1 payload stores -> vmcnt(0) -> __syncthreads ->
// tid0 slot store; payload read = 8 forced asm dwordx4 sc1 (one burst).
//
// WAR safety: publish(t+1) by X follows X's reduce-sync(t), which joins all
// 4 waves' polls(t) (source union = all 64 blocks) and all reads of
// buf[(t-1)&1]; poll(t) passing proves all 64 sources published t, i.e.
// finished THEIR buf[(t-1)&1] reads. Overwriting buf[(t+1)&1] is safe.
__global__ void __launch_bounds__(256, 1)
lstm_scan(const float* __restrict__ emb, const float* __restrict__ W, const float* __restrict__ bW,
          const float* __restrict__ U, const float* __restrict__ bU,
          const float* __restrict__ V, const float* __restrict__ bV,
          float* __restrict__ out, unsigned char* __restrict__ ws)
{
    const int bid  = blockIdx.x;
    const int cb   = bid & 63;    // column group (16 H-cols)
    const int mb   = bid >> 6;    // batch group (16 batches)
    const int tid  = threadIdx.x;
    const int w    = tid >> 6;    // wave id = K-quarter
    const int lane = tid & 63;
    const int fr   = lane & 15;   // A-frag row index
    const int kg   = lane >> 4;   // A-frag k-block

    u64t* pub  = (u64t*)ws;       // [2][64 rows][256 words] 4 f16/word = 256 KB
    char* pubc = (char*)ws;

    __shared__ __align__(16) float part[2][4 * 3 * 64 * 4];   // 2 x 12 KB

    const unsigned e0 = __hip_atomic_load(&slotP[mb][cb][0], __ATOMIC_RELAXED,
                                          __HIP_MEMORY_SCOPE_AGENT);

    // ---- persistent weight fragments (f16, registers): 3 gates x 8 ksteps ----
    // B-frag of mfma_f32_16x16x32_f16: lane l holds B[k=(l>>4)*8+e][n=l&15],
    // B[k][n] = Wgate[16*cb + n][k].  (Layout proven rounds 1/4-19.)
    half8 Bf[3][8];
    {
        const int jrow = cb * 16 + fr;
        const int kb   = w * 256 + kg * 8;
        const float* p0 = W + jrow * H_ + kb;
        const float* p1 = U + jrow * H_ + kb;
        const float* p2 = V + jrow * H_ + kb;
        #pragma unroll
        for (int ks = 0; ks < 8; ++ks) {
            half8 h0, h1, h2;
            #pragma unroll
            for (int e = 0; e < 8; ++e) {
                h0[e] = (_Float16)p0[ks * 32 + e];
                h1[e] = (_Float16)p1[ks * 32 + e];
                h2[e] = (_Float16)p2[ks * 32 + e];
            }
            Bf[0][ks] = h0; Bf[1][ks] = h1; Bf[2][ks] = h2;
        }
    }

    // ---- elementwise ownership: thread -> ONE cell (b, j) ----
    const int rt = tid >> 4;
    const int ct = tid & 15;
    const int b  = mb * 16 + rt;
    const int j  = cb * 16 + ct;
    const float bw = bW[j], bu = bU[j], bv = bV[j];
    const int rl = (rt >> 2) * 16 + ct;   // C/D source lane (proven)
    const int rr = rt & 3;                // C/D source reg

    // publish (r17 verbatim): pack 4 f16 into one 8B sc1 word, drain, join
    // waves, tid0 raises the block slot.
    auto publish = [&](int buf, unsigned slotval, float xin) {
        union { _Float16 h; unsigned short u; } cvp; cvp.h = (_Float16)xin;
        unsigned mine = cvp.u;
        unsigned lo = mine | ((unsigned)__shfl_xor((int)mine, 1) << 16);
        unsigned hi = (unsigned)__shfl_xor((int)lo, 2);
        if ((ct & 3) == 0)
            __hip_atomic_store(&pub[(unsigned)(buf * 16384 + b * 256 + cb * 4 + (ct >> 2))],
                               (u64t)lo | ((u64t)hi << 32),
                               __ATOMIC_RELAXED, __HIP_MEMORY_SCOPE_AGENT);
        asm volatile("s_waitcnt vmcnt(0)" ::: "memory");  // payload acked at LLC
        __syncthreads();
        if (tid == 0)
            __hip_atomic_store(&slotP[mb][cb][0], slotval, __ATOMIC_RELAXED,
                               __HIP_MEMORY_SCOPE_AGENT);
    };

    // per-wave quarter poll: lanes 0..15 poll the wave's 16 source blocks
    // (64B-padded lines, 1 load/slot/retry); __all exits the wave together.
    auto waitq = [&](unsigned tgt) {
        for (;;) {
            unsigned v = tgt;
            if (lane < 16)
                v = __hip_atomic_load(&slotP[mb][w * 16 + lane][0], __ATOMIC_RELAXED,
                                      __HIP_MEMORY_SCOPE_AGENT);
            if (__all((int)(v - tgt) >= 0)) break;
            __builtin_amdgcn_s_sleep(4);   // ~0.1us backoff
        }
        asm volatile("" ::: "memory");
    };

    float p1s = 0.0f;
    float xio = emb[(b * S_ + 0) * H_ + j];    // p2 init = 0
    publish(0, e0 + 1u, xio);
    float embn = emb[(b * S_ + 1) * H_ + j];   // prefetch t=1 (C++: compiler-managed)

    for (int t = 0; t < S_; ++t) {
        waitq(e0 + (unsigned)t + 1u);

        // ---- payload burst: 8 forced dwordx4 sc1 (one round-trip) [r17] ----
        const char* base = pubc + (unsigned)(((t & 1) * 64 + mb * 16 + fr) * 2048
                                             + w * 512 + kg * 16);
        uintx4 q0, q1, q2, q3, q4, q5, q6, q7;
        asm volatile("global_load_dwordx4 %0, %1, off sc1"            : "=v"(q0) : "v"(base));
        asm volatile("global_load_dwordx4 %0, %1, off offset:64 sc1"  : "=v"(q1) : "v"(base));
        asm volatile("global_load_dwordx4 %0, %1, off offset:128 sc1" : "=v"(q2) : "v"(base));
        asm volatile("global_load_dwordx4 %0, %1, off offset:192 sc1" : "=v"(q3) : "v"(base));
        asm volatile("global_load_dwordx4 %0, %1, off offset:256 sc1" : "=v"(q4) : "v"(base));
        asm volatile("global_load_dwordx4 %0, %1, off offset:320 sc1" : "=v"(q5) : "v"(base));
        asm volatile("global_load_dwordx4 %0, %1, off offset:384 sc1" : "=v"(q6) : "v"(base));
        asm volatile("global_load_dwordx4 %0, %1, off offset:448 sc1" : "=v"(q7) : "v"(base));
        asm volatile("s_waitcnt vmcnt(0)" ::: "memory");
        __builtin_amdgcn_sched_barrier(0);   // rule #18: results usable below

        // ---- MFMA from captured registers [r17] ----
        floatx4 a0 = {0.f, 0.f, 0.f, 0.f};
        floatx4 a1 = {0.f, 0.f, 0.f, 0.f};
        floatx4 a2 = {0.f, 0.f, 0.f, 0.f};
        union { uintx4 v; half8 h; } cva;
        #define DO_KS(ks, Q)                                                          \
        {                                                                             \
            cva.v = Q; half8 Af = cva.h;                                              \
            a0 = __builtin_amdgcn_mfma_f32_16x16x32_f16(Af, Bf[0][ks], a0, 0, 0, 0);  \
            a1 = __builtin_amdgcn_mfma_f32_16x16x32_f16(Af, Bf[1][ks], a1, 0, 0, 0);  \
            a2 = __builtin_amdgcn_mfma_f32_16x16x32_f16(Af, Bf[2][ks], a2, 0, 0, 0);  \
        }
        DO_KS(0, q0) DO_KS(1, q1) DO_KS(2, q2) DO_KS(3, q3)
        DO_KS(4, q4) DO_KS(5, q5) DO_KS(6, q6) DO_KS(7, q7)
        #undef DO_KS

        // ---- K-reduction in LDS (double-buffered, one sync) [r17] ----
        float* pp = part[t & 1];
        *(floatx4*)&pp[((w * 3 + 0) * 64 + lane) * 4] = a0;
        *(floatx4*)&pp[((w * 3 + 1) * 64 + lane) * 4] = a1;
        *(floatx4*)&pp[((w * 3 + 2) * 64 + lane) * 4] = a2;
        __syncthreads();

        float pf = bw, pu = bu, pv = bv;
        #pragma unroll
        for (int wv = 0; wv < 4; ++wv) {
            pf += pp[((wv * 3 + 0) * 64 + rl) * 4 + rr];
            pu += pp[((wv * 3 + 1) * 64 + rl) * 4 + rr];
            pv += pp[((wv * 3 + 2) * 64 + rl) * 4 + rr];
        }

        // ---- gates + state update [r17] ----
        float fg = sigmoidf_(pf);
        float ig = sigmoidf_(pu);
        float gg = tanhf_(pv);
        p1s = fg * p1s + ig * gg;
        float p2 = sigmoidf_(xio) * tanhf_(p1s);

        if (t < S_ - 1) {
            float xin = embn + p2;
            xio = xin;
            publish((t + 1) & 1, e0 + (unsigned)t + 2u, xin);
            // after the slot store: these drain during other blocks' polls
            __builtin_nontemporal_store(p2, &out[(b * S_ + t) * H_ + j]);
            if (t + 2 < S_) embn = emb[(b * S_ + t + 2) * H_ + j];
        } else {
            __builtin_nontemporal_store(p2, &out[(b * S_ + t) * H_ + j]);
        }
    }
}

extern "C" void kernel_launch(void* const* d_in, const int* in_sizes, int n_in,
                              void* d_out, int out_size, void* d_ws, size_t ws_size,
                              hipStream_t stream)
{
    const float* emb = (const float*)d_in[0];
    const float* W   = (const float*)d_in[1];
    const float* bWv = (const float*)d_in[2];
    const float* U   = (const float*)d_in[3];
    const float* bUv = (const float*)d_in[4];
    const float* V   = (const float*)d_in[5];
    const float* bVv = (const float*)d_in[6];
    float* outp = (float*)d_out;
    unsigned char* ws = (unsigned char*)d_ws;
    (void)in_sizes; (void)n_in; (void)out_size; (void)ws_size;

    void* args[] = {(void*)&emb, (void*)&W, (void*)&bWv, (void*)&U, (void*)&bUv,
                    (void*)&V, (void*)&bVv, (void*)&outp, (void*)&ws};
    hipError_t err = hipLaunchCooperativeKernel((const void*)lstm_scan,
                                                dim3(256), dim3(256), args, 0, stream);
    if (err != hipSuccess) {
        lstm_scan<<<dim3(256), dim3(256), 0, stream>>>(emb, W, bWv, U, bUv, V, bVv, outp, ws);
    }
}